// Round 7
// baseline (517.949 us; speedup 1.0000x reference)
//
#include <hip/hip_runtime.h>
#include <hip/hip_bf16.h>

#define NG 64       // NUM_GROUPS
#define TOPK 8
#define BM 128      // BLOCK_M
#define NSLOT 65536 // NUM_TOKENS * TOPK
#define HID 4096
#define NTOK 8192
#define NSEG 64     // segments of 1024 ids each

typedef unsigned int v4u __attribute__((ext_vector_type(4)));

// ws ints:
// [0..63]     out_start[e]
// [64..127]   cnt[e]
// [128..191]  padded[e]
// [192..255]  lastslot[e]
// [256]       total
// [320..4415] seg[e*64+b]: K1 writes segcnt, K2 rewrites in place to rank-base
// [4416..8511] lastm_seg[e*64+b]
// rank u16 at ws + 8704 (131072 B) -> scratch ~166 KB

// K1: per-segment histogram + last-slot, no global atomics, no init needed.
__global__ __launch_bounds__(256) void hist_k(const int* __restrict__ ids,
                                              int* __restrict__ ws) {
    __shared__ int h[NG], lm[NG];
    int t = threadIdx.x, b = blockIdx.x;
    if (t < NG) { h[t] = 0; lm[t] = -1; }
    __syncthreads();
    int base = b * 1024;
    for (int i = t; i < 1024; i += 256) {
        int e = ids[base + i] & (NG - 1);
        atomicAdd(&h[e], 1);
        atomicMax(&lm[e], base + i);
    }
    __syncthreads();
    if (t < NG) {
        ws[320 + t * 64 + b] = h[t];
        ws[4416 + t * 64 + b] = lm[t];
    }
}

// K2: one 64-thread block. cnt/padded/lastslot per expert, exclusive scan for
// out_start/total, then per-(e,seg) rank bases in place.
__global__ __launch_bounds__(64) void scan_k(int* __restrict__ ws) {
    int e = threadIdx.x;
    int c = 0, last = -1;
    for (int b = 0; b < NSEG; b++) {
        c += ws[320 + e * 64 + b];
        int l = ws[4416 + e * 64 + b];
        last = l > last ? l : last;
    }
    ws[64 + e] = c;
    ws[128 + e] = (c + BM - 1) / BM * BM;
    ws[192 + e] = last;
    __syncthreads();
    if (e == 0) {
        int acc = 0;
        for (int f = 0; f < NG; f++) { ws[f] = acc; acc += ws[128 + f]; }
        ws[256] = acc;  // total
    }
    __syncthreads();
    int acc = ws[e] - ws[e];  // 0: rank base is within-expert rank
    for (int b = 0; b < NSEG; b++) {
        int sc = ws[320 + e * 64 + b];
        ws[320 + e * 64 + b] = acc;
        acc += sc;
    }
}

// K3: 4096 waves, wave (e,s) stable-ranks expert e within segment s.
// s==0 waves also fill m_indices (f32 expert id).
__global__ __launch_bounds__(256) void rank_k(const int* __restrict__ ids,
                                              const int* __restrict__ ws,
                                              unsigned short* __restrict__ rank,
                                              float* __restrict__ out) {
    int wid = blockIdx.x * 4 + (threadIdx.x >> 6);
    int lane = threadIdx.x & 63;
    int e = wid >> 6;
    int s = wid & (NSEG - 1);
    int base_r = ws[320 + e * 64 + s];  // within-expert rank base for this segment
    int segbase = s * 1024;
#pragma unroll
    for (int c0 = 0; c0 < 1024; c0 += 512) {
        int id[8];
#pragma unroll
        for (int u = 0; u < 8; u++) id[u] = ids[segbase + c0 + u * 64 + lane];
#pragma unroll
        for (int u = 0; u < 8; u++) {
            unsigned long long m = __ballot(id[u] == e);
            if (id[u] == e)
                rank[segbase + c0 + u * 64 + lane] =
                    (unsigned short)(base_r + __popcll(m & ((1ULL << lane) - 1ULL)));
            base_r += __popcll(m);
        }
    }
    if (s == 0) {
        int o = ws[e], p = ws[128 + e], total = ws[256];
        float* m_out = out + (size_t)total * HID;
        float fe = (float)e;
        for (int t2 = lane; t2 < p; t2 += 64) m_out[o + t2] = fe;
    }
}

// K4: inv_perm[v + sum_{f: last_f < v} pad_f] = pos(v); pads follow each last slot.
__global__ __launch_bounds__(256) void inv_k(const int* __restrict__ ids,
                                             const int* __restrict__ ws,
                                             const unsigned short* __restrict__ rank,
                                             float* __restrict__ out) {
    __shared__ int s_last[NG], s_pad[NG];
    int t = threadIdx.x;
    if (t < NG) {
        s_last[t] = ws[192 + t];
        s_pad[t] = ws[128 + t] - ws[64 + t];
    }
    __syncthreads();
    int total = ws[256];
    float* inv_out = out + (size_t)total * (HID + 1);
    int i = blockIdx.x * 256 + t;
    int e = ids[i] & (NG - 1);
    int pos = ws[e] + (int)rank[i];
    int base = i;
#pragma unroll
    for (int f = 0; f < NG; f++) {
        int l = s_last[f];
        base += (l >= 0 && l < i) ? s_pad[f] : 0;
    }
    if (base < NSLOT) inv_out[base] = (float)pos;
    if (i == s_last[e]) {
        int oc = ws[e] + ws[64 + e];
        int pd = s_pad[e];
        for (int j = 0; j < pd; j++) {
            int idx = base + 1 + j;
            if (idx >= NSLOT) break;
            inv_out[idx] = (float)(oc + j);
        }
    }
}

// K5: scatter rows with bf16->f32 widening (bits = u16<<16), nontemporal stores.
__global__ __launch_bounds__(256) void copy_k(const __hip_bfloat16* __restrict__ hs,
                                              const int* __restrict__ ids,
                                              const int* __restrict__ ws,
                                              const unsigned short* __restrict__ rank,
                                              float* __restrict__ out) {
    int b = blockIdx.x;
    int total = ws[256];
    int srcslot, dst;
    if (b < NSLOT) {
        int e = ids[b] & (NG - 1);
        srcslot = b;
        dst = ws[e] + (int)rank[b];
    } else {
        int q = b - NSLOT;
        int e = q >> 7;
        int j = q & 127;
        int c = ws[64 + e], p = ws[128 + e];
        if (c + j >= p) return;
        srcslot = ws[192 + e];
        dst = ws[e] + c + j;
    }
    if (dst < 0 || dst >= total) return;
    int src = srcslot >> 3;  // /TOPK
    if (src < 0 || src >= NTOK) return;
    const v4u* s = (const v4u*)(hs + (size_t)src * HID);
    v4u* d = (v4u*)(out + (size_t)dst * HID);
    int t = threadIdx.x;
#pragma unroll
    for (int half = 0; half < 2; half++) {
        int v = half * 256 + t;
        v4u w = s[v];
        v4u o1 = {w.x << 16, w.x & 0xFFFF0000u, w.y << 16, w.y & 0xFFFF0000u};
        v4u o2 = {w.z << 16, w.z & 0xFFFF0000u, w.w << 16, w.w & 0xFFFF0000u};
        __builtin_nontemporal_store(o1, d + 2 * v);
        __builtin_nontemporal_store(o2, d + 2 * v + 1);
    }
}

extern "C" void kernel_launch(void* const* d_in, const int* in_sizes, int n_in,
                              void* d_out, int out_size, void* d_ws, size_t ws_size,
                              hipStream_t stream) {
    const __hip_bfloat16* hs = (const __hip_bfloat16*)d_in[0];
    const int* ids = (const int*)d_in[1];
    float* out = (float*)d_out;  // mixed-dtype tuple => harness packs as float32

    int* ws = (int*)d_ws;
    unsigned short* rank = (unsigned short*)(ws + 8704);

    hipLaunchKernelGGL(hist_k, dim3(NSEG), dim3(256), 0, stream, ids, ws);
    hipLaunchKernelGGL(scan_k, dim3(1), dim3(64), 0, stream, ws);
    hipLaunchKernelGGL(rank_k, dim3(NG * NSEG / 4), dim3(256), 0, stream, ids, ws, rank, out);
    hipLaunchKernelGGL(inv_k, dim3(NSLOT / 256), dim3(256), 0, stream, ids, ws, rank, out);
    hipLaunchKernelGGL(copy_k, dim3(NSLOT + NG * BM), dim3(256), 0, stream,
                       hs, ids, ws, rank, out);
}

// Round 8
// 330.670 us; speedup vs baseline: 1.5664x; 1.5664x over previous
//
#include <hip/hip_runtime.h>
#include <hip/hip_bf16.h>

#define NG 64       // NUM_GROUPS
#define TOPK 8
#define BM 128      // BLOCK_M
#define NSLOT 65536 // NUM_TOKENS * TOPK
#define HID 4096
#define NTOK 8192
#define NSEG 64     // segments of 1024 ids each

typedef unsigned int v4u __attribute__((ext_vector_type(4)));

// ws ints:
// [0..63]     out_start[e]
// [64..127]   cnt[e]
// [128..191]  padded[e]
// [192..255]  lastslot[e]
// [256]       total
// [320..4415] seg[e*64+s]: K1 writes segcnt, K2 rewrites to within-expert prefix
// [4416..8511] lastm_seg[e*64+s]
// rank u16 at ws + 8704 ints (131072 B) -> scratch ~166 KB (fit verified: round 7 passed)

// K1: per-segment histogram + last-slot. No global atomics, no init kernel.
__global__ __launch_bounds__(256) void hist_k(const int* __restrict__ ids,
                                              int* __restrict__ ws) {
    __shared__ int h[NG], lm[NG];
    int t = threadIdx.x, s = blockIdx.x;
    if (t < NG) { h[t] = 0; lm[t] = -1; }
    __syncthreads();
    int base = s * 1024;
    for (int i = t; i < 1024; i += 256) {
        int e = ids[base + i] & (NG - 1);
        atomicAdd(&h[e], 1);
        atomicMax(&lm[e], base + i);
    }
    __syncthreads();
    if (t < NG) {
        ws[320 + t * 64 + s] = h[t];
        ws[4416 + t * 64 + s] = lm[t];
    }
}

// K2: one 64-thread block. cnt/padded/lastslot, exclusive scans, per-segment bases.
__global__ __launch_bounds__(64) void scan_k(int* __restrict__ ws) {
    int e = threadIdx.x;
    int c = 0, last = -1;
    for (int b = 0; b < NSEG; b++) {
        c += ws[320 + e * 64 + b];
        int l = ws[4416 + e * 64 + b];
        last = l > last ? l : last;
    }
    ws[64 + e] = c;
    ws[128 + e] = (c + BM - 1) / BM * BM;
    ws[192 + e] = last;
    __syncthreads();
    if (e == 0) {
        int acc = 0;
        for (int f = 0; f < NG; f++) { ws[f] = acc; acc += ws[128 + f]; }
        ws[256] = acc;  // total
    }
    __syncthreads();
    int acc = 0;  // within-expert prefix of segment counts
    for (int b = 0; b < NSEG; b++) {
        int sc = ws[320 + e * 64 + b];
        ws[320 + e * 64 + b] = acc;
        acc += sc;
    }
}

// K3: one wave per segment. Register-distributed per-expert bases (lane e owns
// base[e]); per 64-id chunk, iterate experts via ballot, broadcast base via shfl.
// Full-wave contiguous u16 stores -> each rank[] line written by one wave only.
__global__ __launch_bounds__(64) void rank_k(const int* __restrict__ ids,
                                             const int* __restrict__ ws,
                                             unsigned short* __restrict__ rank) {
    int s = blockIdx.x;
    int lane = threadIdx.x;
    int base = ws[320 + lane * 64 + s];  // lane e: within-expert base for segment s
    int segbase = s * 1024;
    unsigned long long below = (1ULL << lane) - 1ULL;
    for (int c0 = 0; c0 < 1024; c0 += 64) {
        int e = ids[segbase + c0 + lane] & (NG - 1);
        int r = 0;
#pragma unroll 8
        for (int x = 0; x < NG; x++) {
            unsigned long long m = __ballot(e == x);
            if (m) {
                int bx = __shfl(base, x);
                if (e == x) r = bx + __popcll(m & below);
                if (lane == x) base += (int)__popcll(m);
            }
        }
        rank[segbase + c0 + lane] = (unsigned short)r;
    }
}

// K4: inv_perm[v + sum_{f: last_f < v} pad_f] = pos(v); pads follow each last slot.
__global__ __launch_bounds__(256) void inv_k(const int* __restrict__ ids,
                                             const int* __restrict__ ws,
                                             const unsigned short* __restrict__ rank,
                                             float* __restrict__ out) {
    __shared__ int s_last[NG], s_pad[NG];
    int t = threadIdx.x;
    if (t < NG) {
        s_last[t] = ws[192 + t];
        s_pad[t] = ws[128 + t] - ws[64 + t];
    }
    __syncthreads();
    int total = ws[256];
    float* inv_out = out + (size_t)total * (HID + 1);
    int i = blockIdx.x * 256 + t;
    int e = ids[i] & (NG - 1);
    int pos = ws[e] + (int)rank[i];
    int base = i;
#pragma unroll
    for (int f = 0; f < NG; f++) {
        int l = s_last[f];
        base += (l >= 0 && l < i) ? s_pad[f] : 0;
    }
    if (base < NSLOT) inv_out[base] = (float)pos;
    if (i == s_last[e]) {
        int oc = ws[e] + ws[64 + e];
        int pd = s_pad[e];
        for (int j = 0; j < pd; j++) {
            int idx = base + 1 + j;
            if (idx >= NSLOT) break;
            inv_out[idx] = (float)(oc + j);
        }
    }
}

// K5: scatter rows with bf16->f32 widening (bits = u16<<16). Regular stores.
// Also writes m_indices (thread 0), since blocks cover every output row once.
__global__ __launch_bounds__(256) void copy_k(const __hip_bfloat16* __restrict__ hs,
                                              const int* __restrict__ ids,
                                              const int* __restrict__ ws,
                                              const unsigned short* __restrict__ rank,
                                              float* __restrict__ out) {
    int b = blockIdx.x;
    int total = ws[256];
    int srcslot, dst, e;
    if (b < NSLOT) {
        e = ids[b] & (NG - 1);
        srcslot = b;
        dst = ws[e] + (int)rank[b];
    } else {
        int q = b - NSLOT;
        e = q >> 7;
        int j = q & 127;
        int c = ws[64 + e], p = ws[128 + e];
        if (c + j >= p) return;
        srcslot = ws[192 + e];
        dst = ws[e] + c + j;
    }
    if (dst < 0 || dst >= total) return;
    int src = srcslot >> 3;  // /TOPK
    if (src < 0 || src >= NTOK) return;
    int t = threadIdx.x;
    if (t == 0) out[(size_t)total * HID + dst] = (float)e;  // m_indices
    const v4u* s = (const v4u*)(hs + (size_t)src * HID);
    v4u* d = (v4u*)(out + (size_t)dst * HID);
#pragma unroll
    for (int half = 0; half < 2; half++) {
        int v = half * 256 + t;
        v4u w = s[v];
        v4u o1 = {w.x << 16, w.x & 0xFFFF0000u, w.y << 16, w.y & 0xFFFF0000u};
        v4u o2 = {w.z << 16, w.z & 0xFFFF0000u, w.w << 16, w.w & 0xFFFF0000u};
        d[2 * v] = o1;
        d[2 * v + 1] = o2;
    }
}

extern "C" void kernel_launch(void* const* d_in, const int* in_sizes, int n_in,
                              void* d_out, int out_size, void* d_ws, size_t ws_size,
                              hipStream_t stream) {
    const __hip_bfloat16* hs = (const __hip_bfloat16*)d_in[0];
    const int* ids = (const int*)d_in[1];
    float* out = (float*)d_out;  // mixed-dtype tuple => harness packs as float32

    int* ws = (int*)d_ws;
    unsigned short* rank = (unsigned short*)(ws + 8704);

    hipLaunchKernelGGL(hist_k, dim3(NSEG), dim3(256), 0, stream, ids, ws);
    hipLaunchKernelGGL(scan_k, dim3(1), dim3(64), 0, stream, ws);
    hipLaunchKernelGGL(rank_k, dim3(NSEG), dim3(64), 0, stream, ids, ws, rank);
    hipLaunchKernelGGL(inv_k, dim3(NSLOT / 256), dim3(256), 0, stream, ids, ws, rank, out);
    hipLaunchKernelGGL(copy_k, dim3(NSLOT + NG * BM), dim3(256), 0, stream,
                       hs, ids, ws, rank, out);
}

// Round 9
// 308.740 us; speedup vs baseline: 1.6776x; 1.0710x over previous
//
#include <hip/hip_runtime.h>
#include <hip/hip_bf16.h>

#define NG 64       // NUM_GROUPS
#define TOPK 8
#define BM 128      // BLOCK_M
#define NSLOT 65536 // NUM_TOKENS * TOPK
#define HID 4096
#define NTOK 8192
#define NSEG 64     // segments of 1024 ids each

typedef unsigned int v4u __attribute__((ext_vector_type(4)));

// ws ints:
// [0..63]     out_start[e]
// [64..127]   cnt[e]
// [128..191]  padded[e]
// [192..255]  lastslot[e]
// [256]       total
// [320..4415] seg[e*64+s]: K1 segcnt -> K2 within-expert prefix
// [4416..8511] lastm_seg[e*64+s]
// rank u16 at ws + 8704 ints (131072 B) -> scratch ~166 KB

// K1: per-segment histogram + last-slot. No global atomics, no init kernel.
__global__ __launch_bounds__(256) void hist_k(const int* __restrict__ ids,
                                              int* __restrict__ ws) {
    __shared__ int h[NG], lm[NG];
    int t = threadIdx.x, s = blockIdx.x;
    if (t < NG) { h[t] = 0; lm[t] = -1; }
    __syncthreads();
    int base = s * 1024;
    for (int i = t; i < 1024; i += 256) {
        int e = ids[base + i] & (NG - 1);
        atomicAdd(&h[e], 1);
        atomicMax(&lm[e], base + i);
    }
    __syncthreads();
    if (t < NG) {
        ws[320 + t * 64 + s] = h[t];
        ws[4416 + t * 64 + s] = lm[t];
    }
}

// K2: one 64-thread block. cnt/padded/lastslot, exclusive scans, per-segment bases.
__global__ __launch_bounds__(64) void scan_k(int* __restrict__ ws) {
    int e = threadIdx.x;
    int c = 0, last = -1;
    for (int b = 0; b < NSEG; b++) {
        c += ws[320 + e * 64 + b];
        int l = ws[4416 + e * 64 + b];
        last = l > last ? l : last;
    }
    ws[64 + e] = c;
    ws[128 + e] = (c + BM - 1) / BM * BM;
    ws[192 + e] = last;
    __syncthreads();
    if (e == 0) {
        int acc = 0;
        for (int f = 0; f < NG; f++) { ws[f] = acc; acc += ws[128 + f]; }
        ws[256] = acc;  // total
    }
    __syncthreads();
    int acc = 0;  // within-expert prefix of segment counts
    for (int b = 0; b < NSEG; b++) {
        int sc = ws[320 + e * 64 + b];
        ws[320 + e * 64 + b] = acc;
        acc += sc;
    }
}

// K3: one wave per segment; register-distributed per-expert bases (lane e owns
// base[e]); ballot per expert, full-wave contiguous u16 stores.
__global__ __launch_bounds__(64) void rank_k(const int* __restrict__ ids,
                                             const int* __restrict__ ws,
                                             unsigned short* __restrict__ rank) {
    int s = blockIdx.x;
    int lane = threadIdx.x;
    int base = ws[320 + lane * 64 + s];
    int segbase = s * 1024;
    unsigned long long below = (1ULL << lane) - 1ULL;
    for (int c0 = 0; c0 < 1024; c0 += 64) {
        int e = ids[segbase + c0 + lane] & (NG - 1);
        int r = 0;
#pragma unroll 8
        for (int x = 0; x < NG; x++) {
            unsigned long long m = __ballot(e == x);
            if (m) {
                int bx = __shfl(base, x);
                if (e == x) r = bx + __popcll(m & below);
                if (lane == x) base += (int)__popcll(m);
            }
        }
        rank[segbase + c0 + lane] = (unsigned short)r;
    }
}

// K4: inv_perm[v + sum_{f: last_f < v} pad_f] = pos(v); pads follow each last slot.
__global__ __launch_bounds__(256) void inv_k(const int* __restrict__ ids,
                                             const int* __restrict__ ws,
                                             const unsigned short* __restrict__ rank,
                                             float* __restrict__ out) {
    __shared__ int s_last[NG], s_pad[NG];
    int t = threadIdx.x;
    if (t < NG) {
        s_last[t] = ws[192 + t];
        s_pad[t] = ws[128 + t] - ws[64 + t];
    }
    __syncthreads();
    int total = ws[256];
    float* inv_out = out + (size_t)total * (HID + 1);
    int i = blockIdx.x * 256 + t;
    int e = ids[i] & (NG - 1);
    int pos = ws[e] + (int)rank[i];
    int base = i;
#pragma unroll
    for (int f = 0; f < NG; f++) {
        int l = s_last[f];
        base += (l >= 0 && l < i) ? s_pad[f] : 0;
    }
    if (base < NSLOT) inv_out[base] = (float)pos;
    if (i == s_last[e]) {
        int oc = ws[e] + ws[64 + e];
        int pd = s_pad[e];
        for (int j = 0; j < pd; j++) {
            int idx = base + 1 + j;
            if (idx >= NSLOT) break;
            inv_out[idx] = (float)(oc + j);
        }
    }
}

// K5: token-grouped scatter. Block b < NTOK: load token row ONCE, widen once,
// store to all 8 destination rows (+ m_indices). Blocks [NTOK, NTOK+NG*BM): pads.
__global__ __launch_bounds__(256) void copy_k(const __hip_bfloat16* __restrict__ hs,
                                              const int* __restrict__ ids,
                                              const int* __restrict__ ws,
                                              const unsigned short* __restrict__ rank,
                                              float* __restrict__ out) {
    int b = blockIdx.x;
    int total = ws[256];
    int t = threadIdx.x;
    float* m_out = out + (size_t)total * HID;
    if (b < NTOK) {
        const v4u* s = (const v4u*)(hs + (size_t)b * HID);
        v4u w0 = s[t];
        v4u w1 = s[t + 256];
        v4u a0 = {w0.x << 16, w0.x & 0xFFFF0000u, w0.y << 16, w0.y & 0xFFFF0000u};
        v4u a1 = {w0.z << 16, w0.z & 0xFFFF0000u, w0.w << 16, w0.w & 0xFFFF0000u};
        v4u a2 = {w1.x << 16, w1.x & 0xFFFF0000u, w1.y << 16, w1.y & 0xFFFF0000u};
        v4u a3 = {w1.z << 16, w1.z & 0xFFFF0000u, w1.w << 16, w1.w & 0xFFFF0000u};
        int slot0 = b * TOPK;
#pragma unroll
        for (int k = 0; k < TOPK; k++) {
            int e = ids[slot0 + k] & (NG - 1);
            int dst = ws[e] + (int)rank[slot0 + k];
            if (dst < 0 || dst >= total) continue;
            v4u* d = (v4u*)(out + (size_t)dst * HID);
            d[2 * t] = a0;
            d[2 * t + 1] = a1;
            d[2 * (t + 256)] = a2;
            d[2 * (t + 256) + 1] = a3;
            if (t == 0) m_out[dst] = (float)e;
        }
    } else {
        int q = b - NTOK;
        int e = q >> 7;
        int j = q & 127;
        int c = ws[64 + e], p = ws[128 + e];
        if (c + j >= p) return;
        int srcslot = ws[192 + e];
        int dst = ws[e] + c + j;
        if (dst < 0 || dst >= total) return;
        int src = srcslot >> 3;
        if (src < 0 || src >= NTOK) return;
        if (t == 0) m_out[dst] = (float)e;
        const v4u* s = (const v4u*)(hs + (size_t)src * HID);
        v4u* d = (v4u*)(out + (size_t)dst * HID);
#pragma unroll
        for (int half = 0; half < 2; half++) {
            int v = half * 256 + t;
            v4u w = s[v];
            v4u o1 = {w.x << 16, w.x & 0xFFFF0000u, w.y << 16, w.y & 0xFFFF0000u};
            v4u o2 = {w.z << 16, w.z & 0xFFFF0000u, w.w << 16, w.w & 0xFFFF0000u};
            d[2 * v] = o1;
            d[2 * v + 1] = o2;
        }
    }
}

extern "C" void kernel_launch(void* const* d_in, const int* in_sizes, int n_in,
                              void* d_out, int out_size, void* d_ws, size_t ws_size,
                              hipStream_t stream) {
    const __hip_bfloat16* hs = (const __hip_bfloat16*)d_in[0];
    const int* ids = (const int*)d_in[1];
    float* out = (float*)d_out;  // mixed-dtype tuple => harness packs as float32

    int* ws = (int*)d_ws;
    unsigned short* rank = (unsigned short*)(ws + 8704);

    hipLaunchKernelGGL(hist_k, dim3(NSEG), dim3(256), 0, stream, ids, ws);
    hipLaunchKernelGGL(scan_k, dim3(1), dim3(64), 0, stream, ws);
    hipLaunchKernelGGL(rank_k, dim3(NSEG), dim3(64), 0, stream, ids, ws, rank);
    hipLaunchKernelGGL(inv_k, dim3(NSLOT / 256), dim3(256), 0, stream, ids, ws, rank, out);
    hipLaunchKernelGGL(copy_k, dim3(NTOK + NG * BM), dim3(256), 0, stream,
                       hs, ids, ws, rank, out);
}

// Round 10
// 303.928 us; speedup vs baseline: 1.7042x; 1.0158x over previous
//
#include <hip/hip_runtime.h>
#include <hip/hip_bf16.h>

#define NG 64       // NUM_GROUPS
#define TOPK 8
#define BM 128      // BLOCK_M
#define NSLOT 65536 // NUM_TOKENS * TOPK
#define HID 4096
#define NTOK 8192
#define NSEG 64     // segments of 1024 ids each

typedef unsigned int v4u __attribute__((ext_vector_type(4)));

// ws ints:
// [0..63]     out_start[e]
// [64..127]   cnt[e]
// [128..191]  padded[e]
// [192..255]  lastslot[e]
// [256]       total
// [257]       ticket counter (never reset; winner = (old & 63)==63)
// [320..4415] segcnt[e*64+s]
// [4416..8511] lastm[e*64+s]
// rank u16 at ws + 8704 ints (131072 B) -> scratch ~166 KB

// K1: per-segment hist, then last-arriving block performs the expert scan.
__global__ __launch_bounds__(256) void hist_scan_k(const int* __restrict__ ids,
                                                   int* __restrict__ ws) {
    __shared__ int h[NG], lm[NG];
    __shared__ int winner;
    int t = threadIdx.x, s = blockIdx.x;
    if (t < NG) { h[t] = 0; lm[t] = -1; }
    __syncthreads();
    int base = s * 1024;
    for (int i = t; i < 1024; i += 256) {
        int e = ids[base + i] & (NG - 1);
        atomicAdd(&h[e], 1);
        atomicMax(&lm[e], base + i);
    }
    __syncthreads();
    if (t < NG) {
        ws[320 + t * 64 + s] = h[t];
        ws[4416 + t * 64 + s] = lm[t];
    }
    __threadfence();  // device-scope release of this block's segcnt/lastm
    __syncthreads();
    if (t == 0) {
        unsigned old = atomicAdd((unsigned*)&ws[257], 1u);
        winner = ((old & 63u) == 63u) ? 1 : 0;  // exactly one winner per 64 adds
    }
    __syncthreads();
    if (!winner) return;
    __threadfence();  // acquire: all 64 blocks' publishes visible
    if (t < NG) {
        int e = t, c = 0, last = -1;
        for (int b = 0; b < NSEG; b++) {
            c += ws[320 + e * 64 + b];
            int l = ws[4416 + e * 64 + b];
            last = l > last ? l : last;
        }
        ws[64 + e] = c;
        ws[128 + e] = (c + BM - 1) / BM * BM;
        ws[192 + e] = last;
    }
    __syncthreads();
    if (t == 0) {
        int acc = 0;
        for (int f = 0; f < NG; f++) { ws[f] = acc; acc += ws[128 + f]; }
        ws[256] = acc;  // total
    }
}

// K2: one wave per segment; lane e self-computes its within-expert base
// (prefix of segcnt over earlier segments), then ballot-ranks the segment.
// Full-wave contiguous u16 stores (one wave per rank[] line).
__global__ __launch_bounds__(64) void rank_k(const int* __restrict__ ids,
                                             const int* __restrict__ ws,
                                             unsigned short* __restrict__ rank) {
    int s = blockIdx.x;
    int lane = threadIdx.x;
    int base = 0;
    for (int s2 = 0; s2 < s; s2++) base += ws[320 + lane * 64 + s2];
    int segbase = s * 1024;
    unsigned long long below = (1ULL << lane) - 1ULL;
    for (int c0 = 0; c0 < 1024; c0 += 64) {
        int e = ids[segbase + c0 + lane] & (NG - 1);
        int r = 0;
#pragma unroll 8
        for (int x = 0; x < NG; x++) {
            unsigned long long m = __ballot(e == x);
            if (m) {
                int bx = __shfl(base, x);
                if (e == x) r = bx + __popcll(m & below);
                if (lane == x) base += (int)__popcll(m);
            }
        }
        rank[segbase + c0 + lane] = (unsigned short)r;
    }
}

// K3: token-grouped scatter + m_indices + inv_perm (fused as trailing blocks).
// b < NTOK: load token row once, widen bf16->f32, store to its <=8 dst rows.
// NTOK <= b < NTOK+NG*BM: pad rows (repeat expert's last slot row).
// Last NSLOT/256 blocks: inv_perm.
__global__ __launch_bounds__(256) void copy_k(const __hip_bfloat16* __restrict__ hs,
                                              const int* __restrict__ ids,
                                              const int* __restrict__ ws,
                                              const unsigned short* __restrict__ rank,
                                              float* __restrict__ out) {
    __shared__ int s_last[NG], s_pad[NG];
    int b = blockIdx.x;
    int total = ws[256];
    int t = threadIdx.x;
    float* m_out = out + (size_t)total * HID;
    if (b < NTOK) {
        const v4u* s = (const v4u*)(hs + (size_t)b * HID);
        v4u w0 = s[t];
        v4u w1 = s[t + 256];
        v4u a0 = {w0.x << 16, w0.x & 0xFFFF0000u, w0.y << 16, w0.y & 0xFFFF0000u};
        v4u a1 = {w0.z << 16, w0.z & 0xFFFF0000u, w0.w << 16, w0.w & 0xFFFF0000u};
        v4u a2 = {w1.x << 16, w1.x & 0xFFFF0000u, w1.y << 16, w1.y & 0xFFFF0000u};
        v4u a3 = {w1.z << 16, w1.z & 0xFFFF0000u, w1.w << 16, w1.w & 0xFFFF0000u};
        int slot0 = b * TOPK;
#pragma unroll
        for (int k = 0; k < TOPK; k++) {
            int e = ids[slot0 + k] & (NG - 1);
            int dst = ws[e] + (int)rank[slot0 + k];
            if (dst < 0 || dst >= total) continue;
            v4u* d = (v4u*)(out + (size_t)dst * HID);
            d[2 * t] = a0;
            d[2 * t + 1] = a1;
            d[2 * (t + 256)] = a2;
            d[2 * (t + 256) + 1] = a3;
            if (t == 0) m_out[dst] = (float)e;
        }
    } else if (b < NTOK + NG * BM) {
        int q = b - NTOK;
        int e = q >> 7;
        int j = q & 127;
        int c = ws[64 + e], p = ws[128 + e];
        if (c + j >= p) return;
        int srcslot = ws[192 + e];
        int dst = ws[e] + c + j;
        if (dst < 0 || dst >= total) return;
        int src = srcslot >> 3;
        if (src < 0 || src >= NTOK) return;
        if (t == 0) m_out[dst] = (float)e;
        const v4u* s = (const v4u*)(hs + (size_t)src * HID);
        v4u* d = (v4u*)(out + (size_t)dst * HID);
#pragma unroll
        for (int half = 0; half < 2; half++) {
            int v = half * 256 + t;
            v4u w = s[v];
            v4u o1 = {w.x << 16, w.x & 0xFFFF0000u, w.y << 16, w.y & 0xFFFF0000u};
            v4u o2 = {w.z << 16, w.z & 0xFFFF0000u, w.w << 16, w.w & 0xFFFF0000u};
            d[2 * v] = o1;
            d[2 * v + 1] = o2;
        }
    } else {
        // inv_perm: inv[v + sum_{f: last_f < v} pad_f] = pos(v); pads follow last slot.
        if (t < NG) {
            s_last[t] = ws[192 + t];
            s_pad[t] = ws[128 + t] - ws[64 + t];
        }
        __syncthreads();
        float* inv_out = out + (size_t)total * (HID + 1);
        int i = (b - NTOK - NG * BM) * 256 + t;
        int e = ids[i] & (NG - 1);
        int pos = ws[e] + (int)rank[i];
        int base = i;
#pragma unroll
        for (int f = 0; f < NG; f++) {
            int l = s_last[f];
            base += (l >= 0 && l < i) ? s_pad[f] : 0;
        }
        if (base < NSLOT) inv_out[base] = (float)pos;
        if (i == s_last[e]) {
            int oc = ws[e] + ws[64 + e];
            int pd = s_pad[e];
            for (int j = 0; j < pd; j++) {
                int idx = base + 1 + j;
                if (idx >= NSLOT) break;
                inv_out[idx] = (float)(oc + j);
            }
        }
    }
}

extern "C" void kernel_launch(void* const* d_in, const int* in_sizes, int n_in,
                              void* d_out, int out_size, void* d_ws, size_t ws_size,
                              hipStream_t stream) {
    const __hip_bfloat16* hs = (const __hip_bfloat16*)d_in[0];
    const int* ids = (const int*)d_in[1];
    float* out = (float*)d_out;  // mixed-dtype tuple => harness packs as float32

    int* ws = (int*)d_ws;
    unsigned short* rank = (unsigned short*)(ws + 8704);

    hipLaunchKernelGGL(hist_scan_k, dim3(NSEG), dim3(256), 0, stream, ids, ws);
    hipLaunchKernelGGL(rank_k, dim3(NSEG), dim3(64), 0, stream, ids, ws, rank);
    hipLaunchKernelGGL(copy_k, dim3(NTOK + NG * BM + NSLOT / 256), dim3(256), 0, stream,
                       hs, ids, ws, rank, out);
}